// Round 1
// baseline (505.785 us; speedup 1.0000x reference)
//
#include <hip/hip_runtime.h>

// Problem constants (match reference)
#define BATCH   8
#define CDIM    256
#define ODIM    16
#define GRID16  16
#define PADW    17
#define OUT_PER_B (ODIM * PADW * PADW * PADW)   // 16*4913 = 78608

// d_ws layout: [0, 1024) floats = W1b1 packed (c*4 + {w0,w1,w2,b1})
//              [1024, 1024+4096) floats = W2T (c*16 + o)
#define WPACK_FLOATS (1024 + 4096)

// ---------------------------------------------------------------------------
// Pack weights: W1b1[c] = (W1[c,0],W1[c,1],W1[c,2],b1[c]); W2T[c*16+o]=W2[o,c]
__global__ void k_pack(const float* __restrict__ W1, const float* __restrict__ b1,
                       const float* __restrict__ W2, float* __restrict__ wpack) {
    int t = threadIdx.x;               // 256 threads
    float4 v;
    v.x = W1[t * 3 + 0];
    v.y = W1[t * 3 + 1];
    v.z = W1[t * 3 + 2];
    v.w = b1[t];
    reinterpret_cast<float4*>(wpack)[t] = v;
    float* w2t = wpack + 1024;
    for (int i = t; i < CDIM * ODIM; i += 256) {
        int c = i >> 4, o = i & 15;
        w2t[i] = W2[o * CDIM + c];
    }
}

// ---------------------------------------------------------------------------
// Init output: interior (x,y,z < 16) = -inf bits, padding = 0
__global__ void k_init(unsigned* __restrict__ out, int total) {
    int i = blockIdx.x * blockDim.x + threadIdx.x;
    if (i >= total) return;
    int r = i % (PADW * PADW * PADW);
    int z = r % PADW;
    int y = (r / PADW) % PADW;
    int x = r / (PADW * PADW);
    out[i] = (x < GRID16 && y < GRID16 && z < GRID16) ? 0xFF800000u : 0u;
}

// ---------------------------------------------------------------------------
// Float atomic max via int tricks (valid with -inf init)
__device__ __forceinline__ void atomicMaxFloat(float* addr, float v) {
    if (v >= 0.0f)
        atomicMax(reinterpret_cast<int*>(addr), __float_as_int(v));
    else
        atomicMin(reinterpret_cast<unsigned*>(addr), __float_as_uint(v));
}

// ---------------------------------------------------------------------------
// One thread per point: MLP (fp32) + scatter-max into padded out
template <bool PACKED>
__global__ __launch_bounds__(256)
void k_scatter(const float* __restrict__ xin,
               const float* __restrict__ wpack,   // PACKED path
               const float* __restrict__ W1,      // raw fallback
               const float* __restrict__ b1,
               const float* __restrict__ W2,
               const float* __restrict__ b2,
               float* __restrict__ out,
               int npts, int nper) {
    int p = blockIdx.x * 256 + threadIdx.x;
    if (p >= npts) return;

    float x0 = xin[p * 3 + 0];
    float x1 = xin[p * 3 + 1];
    float x2 = xin[p * 3 + 2];

    float acc[ODIM];
#pragma unroll
    for (int o = 0; o < ODIM; ++o) acc[o] = b2[o];

    if (PACKED) {
        const float4* w1 = reinterpret_cast<const float4*>(wpack);
        const float*  w2t = wpack + 1024;
#pragma unroll 4
        for (int c = 0; c < CDIM; ++c) {
            float4 w = w1[c];
            float h = fmaf(w.x, x0, fmaf(w.y, x1, fmaf(w.z, x2, w.w)));
            h = fmaxf(h, 0.0f);
#pragma unroll
            for (int o = 0; o < ODIM; ++o)
                acc[o] = fmaf(w2t[c * ODIM + o], h, acc[o]);
        }
    } else {
#pragma unroll 2
        for (int c = 0; c < CDIM; ++c) {
            float h = fmaf(W1[c * 3 + 0], x0,
                      fmaf(W1[c * 3 + 1], x1,
                      fmaf(W1[c * 3 + 2], x2, b1[c])));
            h = fmaxf(h, 0.0f);
#pragma unroll
            for (int o = 0; o < ODIM; ++o)
                acc[o] = fmaf(W2[o * CDIM + c], h, acc[o]);
        }
    }

    int ix = min(max(static_cast<int>(floorf(x0)), 0), GRID16 - 1);
    int iy = min(max(static_cast<int>(floorf(x1)), 0), GRID16 - 1);
    int iz = min(max(static_cast<int>(floorf(x2)), 0), GRID16 - 1);
    int b  = p / nper;

    size_t base = ((((size_t)b * ODIM) * PADW + ix) * PADW + iy) * PADW + iz;
#pragma unroll
    for (int o = 0; o < ODIM; ++o) {
        atomicMaxFloat(out + base + (size_t)o * (PADW * PADW * PADW), acc[o]);
    }
}

// ---------------------------------------------------------------------------
// Empty cells still hold -inf -> 0
__global__ void k_final(unsigned* __restrict__ out, int total) {
    int i = blockIdx.x * blockDim.x + threadIdx.x;
    if (i >= total) return;
    if (out[i] == 0xFF800000u) out[i] = 0u;
}

// ---------------------------------------------------------------------------
extern "C" void kernel_launch(void* const* d_in, const int* in_sizes, int n_in,
                              void* d_out, int out_size, void* d_ws, size_t ws_size,
                              hipStream_t stream) {
    const float* x  = (const float*)d_in[0];
    const float* W1 = (const float*)d_in[1];
    const float* b1 = (const float*)d_in[2];
    const float* W2 = (const float*)d_in[3];
    const float* b2 = (const float*)d_in[4];
    float* out = (float*)d_out;

    int npts = in_sizes[0] / 3;          // B*N
    int nper = npts / BATCH;             // N
    int total = out_size;                // B * OUT_PER_B

    bool packed = ws_size >= (size_t)WPACK_FLOATS * sizeof(float);
    float* wpack = (float*)d_ws;

    if (packed)
        k_pack<<<1, 256, 0, stream>>>(W1, b1, W2, wpack);

    k_init<<<(total + 255) / 256, 256, 0, stream>>>((unsigned*)out, total);

    int blocks = (npts + 255) / 256;
    if (packed)
        k_scatter<true><<<blocks, 256, 0, stream>>>(x, wpack, W1, b1, W2, b2,
                                                    out, npts, nper);
    else
        k_scatter<false><<<blocks, 256, 0, stream>>>(x, wpack, W1, b1, W2, b2,
                                                     out, npts, nper);

    k_final<<<(total + 255) / 256, 256, 0, stream>>>((unsigned*)out, total);
}

// Round 2
// 154.035 us; speedup vs baseline: 3.2836x; 3.2836x over previous
//
#include <hip/hip_runtime.h>

// Problem constants (match reference)
#define BATCH   8
#define CDIM    256
#define ODIM    16
#define GRID16  16
#define NCELL   4096            // 16*16*16
#define PADW    17
#define PADV    (PADW*PADW*PADW)
#define OS_SPLIT 2              // channel halves
#define OCH     8               // channels per block (ODIM/OS_SPLIT)
#define MAXK    16              // point chunks per batch
#define MAP_NEGINF 0x007FFFFFu  // monotone-mapped -inf

// ws layout: [0, 5120) floats = packed weights
//   [0,1024): W1b1 float4 per c   [1024,5120): W2T [c][16]
// [5120, ...)  : K * BATCH * OS_SPLIT slabs of NCELL*OCH mapped uints
#define PACK_FLOATS 5120
#define SLAB_WORDS  (NCELL * OCH)   // 32768

// ---------------------------------------------------------------------------
// monotone float <-> uint mapping so unsigned max == float max
__device__ __forceinline__ unsigned mapf(float f) {
    unsigned u = __float_as_uint(f);
    return (u & 0x80000000u) ? ~u : (u | 0x80000000u);
}
__device__ __forceinline__ float unmapf(unsigned m) {
    unsigned u = (m & 0x80000000u) ? (m ^ 0x80000000u) : ~m;
    return __uint_as_float(u);
}

// ---------------------------------------------------------------------------
__global__ void k_pack(const float* __restrict__ W1, const float* __restrict__ b1,
                       const float* __restrict__ W2, float* __restrict__ wpack) {
    int t = threadIdx.x;               // 256 threads
    float4 v;
    v.x = W1[t * 3 + 0];
    v.y = W1[t * 3 + 1];
    v.z = W1[t * 3 + 2];
    v.w = b1[t];
    reinterpret_cast<float4*>(wpack)[t] = v;
    float* w2t = wpack + 1024;
    for (int i = t; i < CDIM * ODIM; i += 256) {
        int c = i >> 4, o = i & 15;
        w2t[i] = W2[o * CDIM + c];     // [c][16]
    }
}

// ---------------------------------------------------------------------------
// Privatized scatter: block (k, os, b) -> LDS grid [NCELL][OCH] fp32-mapped.
__global__ __launch_bounds__(1024)
void k_scatter_lds(const float* __restrict__ xin,
                   const float* __restrict__ wpack,
                   const float* __restrict__ b2,
                   unsigned* __restrict__ wsgrid,
                   int nper, int K, int chunk) {
    __shared__ unsigned cm[SLAB_WORDS];      // 128 KiB
    const int k  = blockIdx.x;
    const int os = blockIdx.y;
    const int b  = blockIdx.z;
    const int tid = threadIdx.x;

    for (int i = tid; i < SLAB_WORDS; i += 1024) cm[i] = MAP_NEGINF;
    __syncthreads();

    const float4* w1  = reinterpret_cast<const float4*>(wpack);
    const float*  w2t = wpack + 1024 + os * OCH;   // column slice of [c][16]

    float bb[OCH];
#pragma unroll
    for (int o = 0; o < OCH; ++o) bb[o] = b2[os * OCH + o];

    const int p0 = k * chunk;
    const int p1 = min(p0 + chunk, nper);

    for (int i = p0 + tid; i < p1; i += 1024) {
        const float* xp = xin + ((size_t)b * nper + i) * 3;
        float x0 = xp[0], x1 = xp[1], x2 = xp[2];

        float acc[OCH];
#pragma unroll
        for (int o = 0; o < OCH; ++o) acc[o] = bb[o];

#pragma unroll 4
        for (int c = 0; c < CDIM; ++c) {
            float4 w = w1[c];
            float h = fmaf(w.x, x0, fmaf(w.y, x1, fmaf(w.z, x2, w.w)));
            h = fmaxf(h, 0.0f);
            const float* wr = w2t + c * ODIM;
#pragma unroll
            for (int o = 0; o < OCH; ++o) acc[o] = fmaf(wr[o], h, acc[o]);
        }

        int ix = min(max((int)floorf(x0), 0), GRID16 - 1);
        int iy = min(max((int)floorf(x1), 0), GRID16 - 1);
        int iz = min(max((int)floorf(x2), 0), GRID16 - 1);
        unsigned* base = cm + (((ix << 4) | iy) << 4 | iz) * OCH;
#pragma unroll
        for (int o = 0; o < OCH; ++o) atomicMax(base + o, mapf(acc[o]));
    }
    __syncthreads();

    // flush LDS slab -> private ws copy (plain coalesced writes, uint4)
    unsigned* dst = wsgrid + ((((size_t)k * BATCH + b) * OS_SPLIT) + os) * SLAB_WORDS;
    const uint4* s4 = reinterpret_cast<const uint4*>(cm);
    uint4* d4 = reinterpret_cast<uint4*>(dst);
    for (int i = tid; i < SLAB_WORDS / 4; i += 1024) d4[i] = s4[i];
}

// ---------------------------------------------------------------------------
// Gather-max over K copies, unmap, write padded output interior.
__global__ __launch_bounds__(256)
void k_reduce(const unsigned* __restrict__ wsgrid, float* __restrict__ out, int K) {
    int t = blockIdx.x * 256 + threadIdx.x;
    if (t >= BATCH * NCELL) return;
    int b = t >> 12, cell = t & (NCELL - 1);

    unsigned m[ODIM];
#pragma unroll
    for (int o = 0; o < ODIM; ++o) m[o] = MAP_NEGINF;

    for (int k = 0; k < K; ++k) {
#pragma unroll
        for (int os = 0; os < OS_SPLIT; ++os) {
            const uint4* src = reinterpret_cast<const uint4*>(
                wsgrid + ((((size_t)k * BATCH + b) * OS_SPLIT) + os) * SLAB_WORDS
                + (size_t)cell * OCH);
            uint4 a = src[0], c4 = src[1];
            int ob = os * OCH;
            m[ob+0] = max(m[ob+0], a.x);  m[ob+1] = max(m[ob+1], a.y);
            m[ob+2] = max(m[ob+2], a.z);  m[ob+3] = max(m[ob+3], a.w);
            m[ob+4] = max(m[ob+4], c4.x); m[ob+5] = max(m[ob+5], c4.y);
            m[ob+6] = max(m[ob+6], c4.z); m[ob+7] = max(m[ob+7], c4.w);
        }
    }

    int ix = cell >> 8, iy = (cell >> 4) & 15, iz = cell & 15;
    size_t obase = ((size_t)b * ODIM) * PADV + ((ix * PADW + iy) * PADW + iz);
#pragma unroll
    for (int o = 0; o < ODIM; ++o) {
        unsigned mm = m[o];
        out[obase + (size_t)o * PADV] = (mm == MAP_NEGINF) ? 0.0f : unmapf(mm);
    }
}

// ===========================================================================
// Fallback path (round-1): direct global atomics. Used only if ws too small.
__global__ void k_init(unsigned* __restrict__ out, int total) {
    int i = blockIdx.x * blockDim.x + threadIdx.x;
    if (i >= total) return;
    int r = i % PADV;
    int z = r % PADW, y = (r / PADW) % PADW, x = r / (PADW * PADW);
    out[i] = (x < GRID16 && y < GRID16 && z < GRID16) ? 0xFF800000u : 0u;
}
__device__ __forceinline__ void atomicMaxFloat(float* addr, float v) {
    if (v >= 0.0f) atomicMax(reinterpret_cast<int*>(addr), __float_as_int(v));
    else           atomicMin(reinterpret_cast<unsigned*>(addr), __float_as_uint(v));
}
__global__ __launch_bounds__(256)
void k_scatter_glb(const float* __restrict__ xin,
                   const float* __restrict__ W1, const float* __restrict__ b1,
                   const float* __restrict__ W2, const float* __restrict__ b2,
                   float* __restrict__ out, int npts, int nper) {
    int p = blockIdx.x * 256 + threadIdx.x;
    if (p >= npts) return;
    float x0 = xin[p*3+0], x1 = xin[p*3+1], x2 = xin[p*3+2];
    float acc[ODIM];
#pragma unroll
    for (int o = 0; o < ODIM; ++o) acc[o] = b2[o];
#pragma unroll 2
    for (int c = 0; c < CDIM; ++c) {
        float h = fmaf(W1[c*3+0], x0, fmaf(W1[c*3+1], x1, fmaf(W1[c*3+2], x2, b1[c])));
        h = fmaxf(h, 0.0f);
#pragma unroll
        for (int o = 0; o < ODIM; ++o) acc[o] = fmaf(W2[o*CDIM+c], h, acc[o]);
    }
    int ix = min(max((int)floorf(x0), 0), GRID16-1);
    int iy = min(max((int)floorf(x1), 0), GRID16-1);
    int iz = min(max((int)floorf(x2), 0), GRID16-1);
    int b = p / nper;
    size_t base = ((((size_t)b*ODIM)*PADW + ix)*PADW + iy)*PADW + iz;
#pragma unroll
    for (int o = 0; o < ODIM; ++o)
        atomicMaxFloat(out + base + (size_t)o*PADV, acc[o]);
}
__global__ void k_final(unsigned* __restrict__ out, int total) {
    int i = blockIdx.x * blockDim.x + threadIdx.x;
    if (i >= total) return;
    if (out[i] == 0xFF800000u) out[i] = 0u;
}

// ===========================================================================
extern "C" void kernel_launch(void* const* d_in, const int* in_sizes, int n_in,
                              void* d_out, int out_size, void* d_ws, size_t ws_size,
                              hipStream_t stream) {
    const float* x  = (const float*)d_in[0];
    const float* W1 = (const float*)d_in[1];
    const float* b1 = (const float*)d_in[2];
    const float* W2 = (const float*)d_in[3];
    const float* b2 = (const float*)d_in[4];
    float* out = (float*)d_out;

    int npts = in_sizes[0] / 3;          // B*N
    int nper = npts / BATCH;             // N

    // how many privatized grid copies fit in ws?
    size_t ws_words = ws_size / 4;
    int K = 0;
    if (ws_words > PACK_FLOATS) {
        size_t avail = (ws_words - PACK_FLOATS) / ((size_t)BATCH * OS_SPLIT * SLAB_WORDS);
        K = (int)min((size_t)MAXK, avail);
    }

    if (K >= 1) {
        k_pack<<<1, 256, 0, stream>>>(W1, b1, W2, (float*)d_ws);
        hipMemsetAsync(d_out, 0, (size_t)out_size * sizeof(float), stream);

        unsigned* wsgrid = (unsigned*)d_ws + PACK_FLOATS;
        int chunk = (nper + K - 1) / K;
        dim3 grid(K, OS_SPLIT, BATCH);
        k_scatter_lds<<<grid, 1024, 0, stream>>>(x, (const float*)d_ws, b2,
                                                 wsgrid, nper, K, chunk);

        int rt = BATCH * NCELL;
        k_reduce<<<(rt + 255) / 256, 256, 0, stream>>>(wsgrid, out, K);
    } else {
        // fallback: direct global atomics (round-1 path)
        int total = out_size;
        k_init<<<(total + 255) / 256, 256, 0, stream>>>((unsigned*)out, total);
        int blocks = (npts + 255) / 256;
        k_scatter_glb<<<blocks, 256, 0, stream>>>(x, W1, b1, W2, b2, out, npts, nper);
        k_final<<<(total + 255) / 256, 256, 0, stream>>>((unsigned*)out, total);
    }
}